// Round 7
// baseline (536.757 us; speedup 1.0000x reference)
//
#include <hip/hip_runtime.h>
#include <hip/hip_bf16.h>

// Swin block, B=8 H=W=128 C=192 HEADS=6 WS=8 SS=4 MLP_H=384
// T = 131072 tokens, 2048 windows (256/batch), N=64, hd=32. I/O f32.
//
// r11 (on top of r10): raise proj_mlp occupancy 2->3 blocks/CU via LDS diet.
//   h-tile halved to [32][392] by splitting the MLP into two 32-row passes;
//   xsn stays resident across both passes so A-fragment LDS reads don't grow
//   (only W1/W2 L2 re-reads double - cheap). LDS 78336->53248 B.
//   __launch_bounds__(256,3): cap 170 VGPR; liveness audited <=150 per phase;
//   all z[] indices compile-time (rule #20).

typedef __hip_bfloat16 bf16;
typedef __bf16 bf16x8 __attribute__((ext_vector_type(8)));
typedef __bf16 bf16x4 __attribute__((ext_vector_type(4)));
typedef float f32x4 __attribute__((ext_vector_type(4)));

static __device__ __forceinline__ bf16x8 ldg8(const bf16* p) {
    return *reinterpret_cast<const bf16x8*>(p);
}

// GELU with A&S 7.1.26 erf approximation: |err(erf)| <= ~1.5e-6 (f32),
// far below bf16 storage rounding of h. Branch-free, ~16 VALU ops.
static __device__ __forceinline__ float gelu_f(float x) {
    float z  = x * 0.70710678118654752f;
    float az = __builtin_fabsf(z);
    float t  = __builtin_amdgcn_rcpf(__builtin_fmaf(0.3275911f, az, 1.f));
    float p  = __builtin_fmaf(1.061405429f, t, -1.453152027f);
    p = __builtin_fmaf(p, t, 1.421413741f);
    p = __builtin_fmaf(p, t, -0.284496736f);
    p = __builtin_fmaf(p, t, 0.254829592f);
    p = p * t;
    float e  = __expf(-az * az);
    float er = __builtin_fmaf(-p, e, 1.f);        // erf(|z|)
    er = __builtin_copysignf(er, z);
    return 0.5f * x * (1.f + er);
}

// -------- setup: dst[f*K+c] = bf16(src[f*K+c] * g[c]), g==nullptr -> plain ----
__global__ __launch_bounds__(256) void cvt_scale_kernel(
    const float* __restrict__ src, const float* __restrict__ g,
    bf16* __restrict__ dst, int n, int K)
{
    int i = (blockIdx.x * 256 + threadIdx.x) * 4;
    if (i < n) {
        float4 v = *reinterpret_cast<const float4*>(src + i);
        int c = i % K;
        if (g) { v.x *= g[c]; v.y *= g[c + 1]; v.z *= g[c + 2]; v.w *= g[c + 3]; }
        dst[i]     = __float2bfloat16(v.x);
        dst[i + 1] = __float2bfloat16(v.y);
        dst[i + 2] = __float2bfloat16(v.z);
        dst[i + 3] = __float2bfloat16(v.w);
    }
}

// -------- setup: bout[f] = b0[f] + sum_c beta[c] * W[f*K+c]  (one wave per f) ---
__global__ __launch_bounds__(64) void bias_fold_kernel(
    const float* __restrict__ b0, const float* __restrict__ W,
    const float* __restrict__ beta, float* __restrict__ bout, int K)
{
    int f = blockIdx.x, lane = threadIdx.x;
    float s = 0.f;
    for (int c = lane; c < K; c += 64) s += beta[c] * W[(size_t)f * K + c];
#pragma unroll
    for (int off = 32; off; off >>= 1) s += __shfl_xor(s, off, 64);
    if (lane == 0) bout[f] = b0[f] + s;
}

// -------- setup: bias+mask table, TRANSPOSED: bmT[wm][head][n_k][n_q] ----------
__global__ __launch_bounds__(256) void bm_kernel(
    const float* __restrict__ rpb, const int* __restrict__ rel,
    const float* __restrict__ amask, bf16* __restrict__ bmT)
{
    int wm = blockIdx.x / 6, head = blockIdx.x % 6;
    const float* mrow = amask + (size_t)wm * 4096;
    bf16* o = bmT + (size_t)blockIdx.x * 4096;
    for (int idx = threadIdx.x; idx < 4096; idx += 256) {
        int nk = idx >> 6, nq = idx & 63;
        int t = nq * 64 + nk;
        o[idx] = __float2bfloat16(rpb[rel[t] * 6 + head] + mrow[t]);
    }
}

// ---------------- QKV + fused LN1 ----------------
// block 256 = 4 waves; win = blockIdx. Wave w LayerNorms rows 16w..16w+15
// (once), stages normalized bf16 rows in LDS [64][208], all waves re-read
// A-fragments via ds_read_b128, then GEMM + scatter.
__global__ __launch_bounds__(256) void qkv_ln(
    const float* __restrict__ x, const bf16* __restrict__ W,
    const float* __restrict__ bias, bf16* __restrict__ q,
    bf16* __restrict__ k, bf16* __restrict__ vt)
{
    __shared__ __align__(16) bf16 xs[64][208];
    int wave = threadIdx.x >> 6, lane = threadIdx.x & 63;
    int quad = lane >> 4, l16 = lane & 15;
    int win = blockIdx.x;
    int b = win >> 8, wrem = win & 255, wr = wrem >> 4, wc = wrem & 15;

    // --- LN phase: this thread owns cols quad*8+kk*32 of row wave*16+l16 ---
    {
        int n = wave * 16 + l16;
        int ii = n >> 3, jj = n & 7;
        int h = (wr * 8 + ii + 4) & 127, w2 = (wc * 8 + jj + 4) & 127;
        const float* xp = x + ((size_t)b * 16384 + h * 128 + w2) * 192 + quad * 8;
        float e[48];
        float sum = 0.f, sq = 0.f;
#pragma unroll
        for (int kk = 0; kk < 6; ++kk) {
            float4 u0 = *reinterpret_cast<const float4*>(xp + kk * 32);
            float4 u1 = *reinterpret_cast<const float4*>(xp + kk * 32 + 4);
            e[kk * 8 + 0] = u0.x; e[kk * 8 + 1] = u0.y; e[kk * 8 + 2] = u0.z; e[kk * 8 + 3] = u0.w;
            e[kk * 8 + 4] = u1.x; e[kk * 8 + 5] = u1.y; e[kk * 8 + 6] = u1.z; e[kk * 8 + 7] = u1.w;
#pragma unroll
            for (int j = 0; j < 8; ++j) { float v = e[kk * 8 + j]; sum += v; sq += v * v; }
        }
        sum += __shfl_xor(sum, 16, 64); sum += __shfl_xor(sum, 32, 64);
        sq  += __shfl_xor(sq, 16, 64);  sq  += __shfl_xor(sq, 32, 64);
        float mean = sum * (1.f / 192.f);
        float rstd = rsqrtf(sq * (1.f / 192.f) - mean * mean + 1e-5f);
#pragma unroll
        for (int kk = 0; kk < 6; ++kk) {
            bf16x8 pk;
#pragma unroll
            for (int j = 0; j < 8; ++j)
                pk[j] = (__bf16)((e[kk * 8 + j] - mean) * rstd);
            *reinterpret_cast<bf16x8*>(&xs[n][kk * 32 + quad * 8]) = pk;
        }
    }
    __syncthreads();
    // --- load A fragments from LDS (shared across waves) ---
    bf16x8 a[4][6];
#pragma unroll
    for (int mt = 0; mt < 4; ++mt)
#pragma unroll
        for (int kk = 0; kk < 6; ++kk)
            a[mt][kk] = *reinterpret_cast<const bf16x8*>(&xs[mt * 16 + l16][kk * 32 + quad * 8]);

#pragma unroll 1
    for (int i = 0; i < 9; ++i) {
        int nt = wave * 9 + i;
        const bf16* wrow = W + (size_t)(nt * 16 + l16) * 192 + quad * 8;
        bf16x8 bfr[6];
#pragma unroll
        for (int kk = 0; kk < 6; ++kk) bfr[kk] = ldg8(wrow + kk * 32);
        f32x4 acc[4];
#pragma unroll
        for (int mt = 0; mt < 4; ++mt) {
            f32x4 z = {0.f, 0.f, 0.f, 0.f};
#pragma unroll
            for (int kk = 0; kk < 6; ++kk)
                z = __builtin_amdgcn_mfma_f32_16x16x32_bf16(a[mt][kk], bfr[kk], z, 0, 0, 0);
            acc[mt] = z;
        }
        int f = nt * 16 + l16;
        float bb = bias[f];
        int which = f / 192;           // uniform per (wave,i)
        int head = (f % 192) >> 5;
        int d = f & 31;
        size_t wh2 = (size_t)(win * 6 + head) * 2048;
        if (which == 2) {
            // lane holds 4 CONSECUTIVE n for fixed d -> one 8B store per mt
#pragma unroll
            for (int mt = 0; mt < 4; ++mt) {
                bf16x4 pk;
#pragma unroll
                for (int r = 0; r < 4; ++r) pk[r] = (__bf16)(acc[mt][r] + bb);
                *reinterpret_cast<bf16x4*>(vt + wh2 + d * 64 + mt * 16 + quad * 4) = pk;
            }
        } else {
            float sc = (which == 0) ? 0.17677669529663687f : 1.f;
            bf16* dst = (which == 1) ? k : q;
#pragma unroll
            for (int mt = 0; mt < 4; ++mt)
#pragma unroll
                for (int r = 0; r < 4; ++r) {
                    int n = mt * 16 + quad * 4 + r;
                    dst[wh2 + n * 32 + d] = __float2bfloat16((acc[mt][r] + bb) * sc);
                }
        }
    }
}

// ---------------- Attention (MFMA): one wave per (win, head) ----------------
__global__ __launch_bounds__(256) void attn_kernel(
    const bf16* __restrict__ q, const bf16* __restrict__ k,
    const bf16* __restrict__ vt, const bf16* __restrict__ bmT,
    bf16* __restrict__ ao)
{
    __shared__ __align__(16) bf16 lds[4][64 * 72];
    int wave = threadIdx.x >> 6, lane = threadIdx.x & 63;
    int quad = lane >> 4, l16 = lane & 15;
    int wh = blockIdx.x * 4 + wave;
    int win = wh / 6, head = wh - win * 6;
    const bf16* Qp = q + (size_t)wh * 2048;
    const bf16* Kp = k + (size_t)wh * 2048;
    const bf16* Vp = vt + (size_t)wh * 2048;
    const bf16* bm = bmT + (size_t)((win & 255) * 6 + head) * 4096;

    bf16x8 kf[4], qf[4];
#pragma unroll
    for (int t = 0; t < 4; ++t) {
        kf[t] = ldg8(Kp + (t * 16 + l16) * 32 + quad * 8);
        qf[t] = ldg8(Qp + (t * 16 + l16) * 32 + quad * 8);
    }
    f32x4 s[4][4];
#pragma unroll
    for (int mt = 0; mt < 4; ++mt)
#pragma unroll
        for (int nt = 0; nt < 4; ++nt) {
            f32x4 z = {0.f, 0.f, 0.f, 0.f};
            s[mt][nt] = __builtin_amdgcn_mfma_f32_16x16x32_bf16(kf[mt], qf[nt], z, 0, 0, 0);
        }
#pragma unroll
    for (int mt = 0; mt < 4; ++mt)
#pragma unroll
        for (int nt = 0; nt < 4; ++nt)
#pragma unroll
            for (int r = 0; r < 4; ++r) {
                int nk = mt * 16 + quad * 4 + r, nq = nt * 16 + l16;
                s[mt][nt][r] += __bfloat162float(bm[nk * 64 + nq]);
            }
    float linv[4];
#pragma unroll
    for (int nt = 0; nt < 4; ++nt) {
        float mx = -3.0e38f;
#pragma unroll
        for (int mt = 0; mt < 4; ++mt)
#pragma unroll
            for (int r = 0; r < 4; ++r) mx = fmaxf(mx, s[mt][nt][r]);
        mx = fmaxf(mx, __shfl_xor(mx, 16, 64));
        mx = fmaxf(mx, __shfl_xor(mx, 32, 64));
        float sum = 0.f;
#pragma unroll
        for (int mt = 0; mt < 4; ++mt)
#pragma unroll
            for (int r = 0; r < 4; ++r) {
                float p = __expf(s[mt][nt][r] - mx);
                s[mt][nt][r] = p;
                sum += p;
            }
        sum += __shfl_xor(sum, 16, 64);
        sum += __shfl_xor(sum, 32, 64);
        linv[nt] = 1.f / sum;
    }
    // write P[n_q][n_k] * (1/l) to LDS (stride 72)
    bf16* lp = lds[wave];
#pragma unroll
    for (int mt = 0; mt < 4; ++mt)
#pragma unroll
        for (int nt = 0; nt < 4; ++nt)
#pragma unroll
            for (int r = 0; r < 4; ++r)
                lp[(nt * 16 + l16) * 72 + mt * 16 + quad * 4 + r] =
                    __float2bfloat16(s[mt][nt][r] * linv[nt]);
    f32x4 o[4][2];
#pragma unroll
    for (int mo = 0; mo < 4; ++mo)
#pragma unroll
        for (int no = 0; no < 2; ++no) o[mo][no] = (f32x4){0.f, 0.f, 0.f, 0.f};
#pragma unroll
    for (int kh = 0; kh < 2; ++kh) {
        bf16x8 pf[4];
#pragma unroll
        for (int mo = 0; mo < 4; ++mo)
            pf[mo] = *reinterpret_cast<const bf16x8*>(
                lp + (mo * 16 + l16) * 72 + kh * 32 + quad * 8);
#pragma unroll
        for (int no = 0; no < 2; ++no) {
            bf16x8 vf = ldg8(Vp + (no * 16 + l16) * 64 + kh * 32 + quad * 8);
#pragma unroll
            for (int mo = 0; mo < 4; ++mo)
                o[mo][no] = __builtin_amdgcn_mfma_f32_16x16x32_bf16(pf[mo], vf, o[mo][no], 0, 0, 0);
        }
    }
    // store to ao[wh][n][32]
    bf16* ob = ao + (size_t)wh * 2048;
#pragma unroll
    for (int mo = 0; mo < 4; ++mo)
#pragma unroll
        for (int r = 0; r < 4; ++r) {
            int nq = mo * 16 + quad * 4 + r;
            ob[nq * 32 + l16]      = __float2bfloat16(o[mo][0][r]);
            ob[nq * 32 + 16 + l16] = __float2bfloat16(o[mo][1][r]);
        }
}

// ------ Fused proj + LN2 + MLP: one window per block, x1 lives in registers ----
// r11: MLP split into two 32-row passes; hsh halved; xsn resident across both.
// phases: A proj GEMM -> B residual -> C LN2 stats -> D xn to xsn ->
// per half: {E fc1+GELU (h[32] to hsh) -> F fc2 + x1(regs) residual -> out}.
__global__ __launch_bounds__(256, 3) void proj_mlp(
    const bf16* __restrict__ ao, const bf16* __restrict__ Wp,
    const float* __restrict__ pb, const float* __restrict__ x,
    const bf16* __restrict__ W1, const float* __restrict__ b1,
    const bf16* __restrict__ W2, const float* __restrict__ b2,
    float* __restrict__ out)
{
    __shared__ __align__(16) bf16 xsn[64 * 200];     // 25600 B
    __shared__ __align__(16) bf16 hsh[32 * 392];     // 25088 B
    __shared__ float part[4][64], part2[4][64], ms[64][2];   // 2560 B
    int wave = threadIdx.x >> 6, lane = threadIdx.x & 63;
    int quad = lane >> 4, l16 = lane & 15;
    int win = blockIdx.x;
    int b = win >> 8, wrem = win & 255, wr = wrem >> 4, wc = wrem & 15;

    // ---- phase A: proj GEMM; z[i][mt] = x1 tile slice (stays in regs) ----
    f32x4 z[3][4];
    {
        bf16x8 bw[3][6];
#pragma unroll
        for (int i = 0; i < 3; ++i) {
            const bf16* wp = Wp + (size_t)((wave * 3 + i) * 16 + l16) * 192 + quad * 8;
#pragma unroll
            for (int kk = 0; kk < 6; ++kk) bw[i][kk] = ldg8(wp + kk * 32);
        }
#pragma unroll
        for (int mt = 0; mt < 4; ++mt) {
            bf16x8 a6[6];
#pragma unroll
            for (int h = 0; h < 6; ++h)
                a6[h] = ldg8(ao + (size_t)(win * 6 + h) * 2048 + (mt * 16 + l16) * 32 + quad * 8);
#pragma unroll
            for (int i = 0; i < 3; ++i) {
                f32x4 zz = {0.f, 0.f, 0.f, 0.f};
#pragma unroll
                for (int kk = 0; kk < 6; ++kk)
                    zz = __builtin_amdgcn_mfma_f32_16x16x32_bf16(a6[kk], bw[i][kk], zz, 0, 0, 0);
                z[i][mt] = zz;
            }
        }
    }
    // ---- phase B: x1 = proj + pb + x_perm ----
#pragma unroll
    for (int i = 0; i < 3; ++i) {
        int c = (wave * 3 + i) * 16 + l16;
        float bb = pb[c];
#pragma unroll
        for (int mt = 0; mt < 4; ++mt)
#pragma unroll
            for (int r = 0; r < 4; ++r) {
                int n = mt * 16 + quad * 4 + r;
                int ii = n >> 3, jj = n & 7;
                int h = (wr * 8 + ii + 4) & 127, w2 = (wc * 8 + jj + 4) & 127;
                size_t sidx = ((size_t)b * 16384 + h * 128 + w2) * 192 + c;
                z[i][mt][r] += bb + x[sidx];
            }
    }
    // ---- phase C: LN2 stats (cross-wave via LDS partials) ----
#pragma unroll
    for (int mt = 0; mt < 4; ++mt)
#pragma unroll
        for (int r = 0; r < 4; ++r) {
            float s1 = 0.f, s2 = 0.f;
#pragma unroll
            for (int i = 0; i < 3; ++i) {
                float v = z[i][mt][r];
                s1 += v; s2 += v * v;
            }
#pragma unroll
            for (int off = 1; off < 16; off <<= 1) {
                s1 += __shfl_xor(s1, off, 64);
                s2 += __shfl_xor(s2, off, 64);
            }
            if (l16 == 0) {
                int row = mt * 16 + quad * 4 + r;
                part[wave][row] = s1;
                part2[wave][row] = s2;
            }
        }
    __syncthreads();
    if (threadIdx.x < 64) {
        int t = threadIdx.x;
        float S = part[0][t] + part[1][t] + part[2][t] + part[3][t];
        float S2 = part2[0][t] + part2[1][t] + part2[2][t] + part2[3][t];
        float m = S * (1.f / 192.f);
        ms[t][0] = m;
        ms[t][1] = rsqrtf(S2 * (1.f / 192.f) - m * m + 1e-5f);
    }
    __syncthreads();
    // ---- phase D: write normalized bf16 tile to xsn ----
#pragma unroll
    for (int i = 0; i < 3; ++i) {
        int c = (wave * 3 + i) * 16 + l16;
#pragma unroll
        for (int mt = 0; mt < 4; ++mt)
#pragma unroll
            for (int r = 0; r < 4; ++r) {
                int row = mt * 16 + quad * 4 + r;
                xsn[row * 200 + c] =
                    __float2bfloat16((z[i][mt][r] - ms[row][0]) * ms[row][1]);
            }
    }
    __syncthreads();
    // ---- two 32-row MLP passes ----
#pragma unroll
    for (int half = 0; half < 2; ++half) {
        // -- fc1 + GELU for rows half*32 .. half*32+31 -> hsh[32][392] --
        {
            bf16x8 a2[2][6];
#pragma unroll
            for (int mh = 0; mh < 2; ++mh)
#pragma unroll
                for (int kk = 0; kk < 6; ++kk)
                    a2[mh][kk] = *reinterpret_cast<const bf16x8*>(
                        &xsn[((half * 2 + mh) * 16 + l16) * 200 + kk * 32 + quad * 8]);
#pragma unroll 1
            for (int i = 0; i < 6; ++i) {
                int nt = wave * 6 + i;
                const bf16* wp = W1 + (size_t)(nt * 16 + l16) * 192 + quad * 8;
                bf16x8 bfr[6];
#pragma unroll
                for (int kk = 0; kk < 6; ++kk) bfr[kk] = ldg8(wp + kk * 32);
                float bb = b1[nt * 16 + l16];
#pragma unroll
                for (int mh = 0; mh < 2; ++mh) {
                    f32x4 zz = {0.f, 0.f, 0.f, 0.f};
#pragma unroll
                    for (int kk = 0; kk < 6; ++kk)
                        zz = __builtin_amdgcn_mfma_f32_16x16x32_bf16(a2[mh][kk], bfr[kk], zz, 0, 0, 0);
#pragma unroll
                    for (int r = 0; r < 4; ++r) {
                        float gl = gelu_f(zz[r] + bb);
                        hsh[(mh * 16 + quad * 4 + r) * 392 + nt * 16 + l16] = __float2bfloat16(gl);
                    }
                }
            }
        }
        __syncthreads();
        // -- fc2 + b2 + x1(regs) -> scatter to out, same 32 rows --
#pragma unroll
        for (int j = 0; j < 3; ++j) {
            int c = (wave * 3 + j) * 16 + l16;
            const bf16* wp = W2 + (size_t)c * 384 + quad * 8;
            bf16x8 bw[12];
#pragma unroll
            for (int kk = 0; kk < 12; ++kk) bw[kk] = ldg8(wp + kk * 32);
            float bb = b2[c];
#pragma unroll
            for (int mh = 0; mh < 2; ++mh) {
                f32x4 zz = {0.f, 0.f, 0.f, 0.f};
#pragma unroll
                for (int kk = 0; kk < 12; ++kk) {
                    bf16x8 pa = *reinterpret_cast<const bf16x8*>(
                        &hsh[(mh * 16 + l16) * 392 + kk * 32 + quad * 8]);
                    zz = __builtin_amdgcn_mfma_f32_16x16x32_bf16(pa, bw[kk], zz, 0, 0, 0);
                }
#pragma unroll
                for (int r = 0; r < 4; ++r) {
                    int row = half * 32 + mh * 16 + quad * 4 + r;
                    int ii = row >> 3, jj = row & 7;
                    int h = (wr * 8 + ii + 4) & 127, w2c = (wc * 8 + jj + 4) & 127;
                    size_t didx = ((size_t)b * 16384 + h * 128 + w2c) * 192 + c;
                    out[didx] = zz[r] + bb + z[j][half * 2 + mh][r];
                }
            }
        }
        __syncthreads();   // protect hsh before next half's fc1 writes
    }
}

extern "C" void kernel_launch(void* const* d_in, const int* in_sizes, int n_in,
                              void* d_out, int out_size, void* d_ws, size_t ws_size,
                              hipStream_t stream)
{
    const float* x     = (const float*)d_in[0];
    const float* n1g   = (const float*)d_in[1];
    const float* n1b   = (const float*)d_in[2];
    const float* qkvw  = (const float*)d_in[3];
    const float* qkvb  = (const float*)d_in[4];
    const float* rpb   = (const float*)d_in[5];
    const float* projw = (const float*)d_in[6];
    const float* projb = (const float*)d_in[7];
    const float* n2g   = (const float*)d_in[8];
    const float* n2b   = (const float*)d_in[9];
    const float* fc1w  = (const float*)d_in[10];
    const float* fc1b  = (const float*)d_in[11];
    const float* fc2w  = (const float*)d_in[12];
    const float* fc2b  = (const float*)d_in[13];
    const int*   rel   = (const int*)d_in[14];
    const float* amask = (const float*)d_in[15];
    float* out = (float*)d_out;

    char* ws = (char*)d_ws;
    const size_t SZ = (size_t)131072 * 192 * 2;   // 50,331,648 B per bf16 [T,192]
    bf16* qb  = (bf16*)(ws);                       // q
    bf16* kb  = (bf16*)(ws + SZ);                  // k
    bf16* vtb = (bf16*)(ws + 2 * SZ);              // vt
    bf16* aob = (bf16*)(ws + 3 * SZ);              // attention out
    char* wreg = ws + 4 * SZ;
    bf16*  wq  = (bf16*)(wreg);                    // 110592 el
    bf16*  wp  = wq + 110592;                      // 36864
    bf16*  w1  = wp + 36864;                       // 73728
    bf16*  w2  = w1 + 73728;                       // 73728
    float* bq  = (float*)(w2 + 73728);             // 576 f32
    float* b1  = bq + 576;                         // 384 f32
    bf16*  bmT = (bf16*)(b1 + 384);                // 6,291,456 el (12.6 MB)

    // setup (tiny)
    cvt_scale_kernel<<<108, 256, 0, stream>>>(qkvw, n1g, wq, 110592, 192);
    cvt_scale_kernel<<<36, 256, 0, stream>>>(projw, nullptr, wp, 36864, 192);
    cvt_scale_kernel<<<72, 256, 0, stream>>>(fc1w, n2g, w1, 73728, 192);
    cvt_scale_kernel<<<72, 256, 0, stream>>>(fc2w, nullptr, w2, 73728, 384);
    bias_fold_kernel<<<576, 64, 0, stream>>>(qkvb, qkvw, n1b, bq, 192);
    bias_fold_kernel<<<384, 64, 0, stream>>>(fc1b, fc1w, n2b, b1, 192);
    bm_kernel<<<1536, 256, 0, stream>>>(rpb, rel, amask, bmT);
    // main pipeline
    qkv_ln<<<2048, 256, 0, stream>>>(x, wq, bq, qb, kb, vtb);
    attn_kernel<<<3072, 256, 0, stream>>>(qb, kb, vtb, bmT, aob);
    proj_mlp<<<2048, 256, 0, stream>>>(aob, wp, projb, x, w1, b1, w2, fc2b, out);
}

// Round 8
// 507.462 us; speedup vs baseline: 1.0577x; 1.0577x over previous
//
#include <hip/hip_runtime.h>
#include <hip/hip_bf16.h>

// Swin block, B=8 H=W=128 C=192 HEADS=6 WS=8 SS=4 MLP_H=384
// T = 131072 tokens, 2048 windows (256/batch), N=64, hd=32. I/O f32.
//
// r12: revert r11 row-split (occupancy up but dur 184->211: kernel is
//   per-wave-latency-bound, confirmed twice now). r10 structure +:
//   - proj_mlp phase B: x residual gathered via LDS staging (union with hsh:
//     f32 zt[64][196] == 50176 B). 12 vectorized float4 loads/thread issued
//     BEFORE phase A (latency hides under proj GEMM); scattered reads from
//     LDS instead of 48 scalar L3 loads in the serial chain.
//   - bmT layout [nq][nk] (bm_kernel = identity map) -> attn reads bias as
//     16x bf16x4 instead of 64x 2B scalars.

typedef __hip_bfloat16 bf16;
typedef __bf16 bf16x8 __attribute__((ext_vector_type(8)));
typedef __bf16 bf16x4 __attribute__((ext_vector_type(4)));
typedef float f32x4 __attribute__((ext_vector_type(4)));

static __device__ __forceinline__ bf16x8 ldg8(const bf16* p) {
    return *reinterpret_cast<const bf16x8*>(p);
}

// GELU with A&S 7.1.26 erf approximation: |err(erf)| <= ~1.5e-6 (f32),
// far below bf16 storage rounding of h. Branch-free, ~16 VALU ops.
static __device__ __forceinline__ float gelu_f(float x) {
    float z  = x * 0.70710678118654752f;
    float az = __builtin_fabsf(z);
    float t  = __builtin_amdgcn_rcpf(__builtin_fmaf(0.3275911f, az, 1.f));
    float p  = __builtin_fmaf(1.061405429f, t, -1.453152027f);
    p = __builtin_fmaf(p, t, 1.421413741f);
    p = __builtin_fmaf(p, t, -0.284496736f);
    p = __builtin_fmaf(p, t, 0.254829592f);
    p = p * t;
    float e  = __expf(-az * az);
    float er = __builtin_fmaf(-p, e, 1.f);        // erf(|z|)
    er = __builtin_copysignf(er, z);
    return 0.5f * x * (1.f + er);
}

// -------- setup: dst[f*K+c] = bf16(src[f*K+c] * g[c]), g==nullptr -> plain ----
__global__ __launch_bounds__(256) void cvt_scale_kernel(
    const float* __restrict__ src, const float* __restrict__ g,
    bf16* __restrict__ dst, int n, int K)
{
    int i = (blockIdx.x * 256 + threadIdx.x) * 4;
    if (i < n) {
        float4 v = *reinterpret_cast<const float4*>(src + i);
        int c = i % K;
        if (g) { v.x *= g[c]; v.y *= g[c + 1]; v.z *= g[c + 2]; v.w *= g[c + 3]; }
        dst[i]     = __float2bfloat16(v.x);
        dst[i + 1] = __float2bfloat16(v.y);
        dst[i + 2] = __float2bfloat16(v.z);
        dst[i + 3] = __float2bfloat16(v.w);
    }
}

// -------- setup: bout[f] = b0[f] + sum_c beta[c] * W[f*K+c]  (one wave per f) ---
__global__ __launch_bounds__(64) void bias_fold_kernel(
    const float* __restrict__ b0, const float* __restrict__ W,
    const float* __restrict__ beta, float* __restrict__ bout, int K)
{
    int f = blockIdx.x, lane = threadIdx.x;
    float s = 0.f;
    for (int c = lane; c < K; c += 64) s += beta[c] * W[(size_t)f * K + c];
#pragma unroll
    for (int off = 32; off; off >>= 1) s += __shfl_xor(s, off, 64);
    if (lane == 0) bout[f] = b0[f] + s;
}

// -------- setup: bias+mask table, layout [wm][head][n_q][n_k] ----------------
__global__ __launch_bounds__(256) void bm_kernel(
    const float* __restrict__ rpb, const int* __restrict__ rel,
    const float* __restrict__ amask, bf16* __restrict__ bmT)
{
    int wm = blockIdx.x / 6, head = blockIdx.x % 6;
    const float* mrow = amask + (size_t)wm * 4096;
    bf16* o = bmT + (size_t)blockIdx.x * 4096;
    for (int idx = threadIdx.x; idx < 4096; idx += 256) {
        // rel/amask are [nq][nk]; keep that order so the consumer can
        // vector-load 4 consecutive nk.
        o[idx] = __float2bfloat16(rpb[rel[idx] * 6 + head] + mrow[idx]);
    }
}

// ---------------- QKV + fused LN1 ----------------
// block 256 = 4 waves; win = blockIdx. Wave w LayerNorms rows 16w..16w+15
// (once), stages normalized bf16 rows in LDS [64][208], all waves re-read
// A-fragments via ds_read_b128, then GEMM + scatter.
__global__ __launch_bounds__(256) void qkv_ln(
    const float* __restrict__ x, const bf16* __restrict__ W,
    const float* __restrict__ bias, bf16* __restrict__ q,
    bf16* __restrict__ k, bf16* __restrict__ vt)
{
    __shared__ __align__(16) bf16 xs[64][208];
    int wave = threadIdx.x >> 6, lane = threadIdx.x & 63;
    int quad = lane >> 4, l16 = lane & 15;
    int win = blockIdx.x;
    int b = win >> 8, wrem = win & 255, wr = wrem >> 4, wc = wrem & 15;

    // --- LN phase: this thread owns cols quad*8+kk*32 of row wave*16+l16 ---
    {
        int n = wave * 16 + l16;
        int ii = n >> 3, jj = n & 7;
        int h = (wr * 8 + ii + 4) & 127, w2 = (wc * 8 + jj + 4) & 127;
        const float* xp = x + ((size_t)b * 16384 + h * 128 + w2) * 192 + quad * 8;
        float e[48];
        float sum = 0.f, sq = 0.f;
#pragma unroll
        for (int kk = 0; kk < 6; ++kk) {
            float4 u0 = *reinterpret_cast<const float4*>(xp + kk * 32);
            float4 u1 = *reinterpret_cast<const float4*>(xp + kk * 32 + 4);
            e[kk * 8 + 0] = u0.x; e[kk * 8 + 1] = u0.y; e[kk * 8 + 2] = u0.z; e[kk * 8 + 3] = u0.w;
            e[kk * 8 + 4] = u1.x; e[kk * 8 + 5] = u1.y; e[kk * 8 + 6] = u1.z; e[kk * 8 + 7] = u1.w;
#pragma unroll
            for (int j = 0; j < 8; ++j) { float v = e[kk * 8 + j]; sum += v; sq += v * v; }
        }
        sum += __shfl_xor(sum, 16, 64); sum += __shfl_xor(sum, 32, 64);
        sq  += __shfl_xor(sq, 16, 64);  sq  += __shfl_xor(sq, 32, 64);
        float mean = sum * (1.f / 192.f);
        float rstd = rsqrtf(sq * (1.f / 192.f) - mean * mean + 1e-5f);
#pragma unroll
        for (int kk = 0; kk < 6; ++kk) {
            bf16x8 pk;
#pragma unroll
            for (int j = 0; j < 8; ++j)
                pk[j] = (__bf16)((e[kk * 8 + j] - mean) * rstd);
            *reinterpret_cast<bf16x8*>(&xs[n][kk * 32 + quad * 8]) = pk;
        }
    }
    __syncthreads();
    // --- load A fragments from LDS (shared across waves) ---
    bf16x8 a[4][6];
#pragma unroll
    for (int mt = 0; mt < 4; ++mt)
#pragma unroll
        for (int kk = 0; kk < 6; ++kk)
            a[mt][kk] = *reinterpret_cast<const bf16x8*>(&xs[mt * 16 + l16][kk * 32 + quad * 8]);

#pragma unroll 1
    for (int i = 0; i < 9; ++i) {
        int nt = wave * 9 + i;
        const bf16* wrow = W + (size_t)(nt * 16 + l16) * 192 + quad * 8;
        bf16x8 bfr[6];
#pragma unroll
        for (int kk = 0; kk < 6; ++kk) bfr[kk] = ldg8(wrow + kk * 32);
        f32x4 acc[4];
#pragma unroll
        for (int mt = 0; mt < 4; ++mt) {
            f32x4 z = {0.f, 0.f, 0.f, 0.f};
#pragma unroll
            for (int kk = 0; kk < 6; ++kk)
                z = __builtin_amdgcn_mfma_f32_16x16x32_bf16(a[mt][kk], bfr[kk], z, 0, 0, 0);
            acc[mt] = z;
        }
        int f = nt * 16 + l16;
        float bb = bias[f];
        int which = f / 192;           // uniform per (wave,i)
        int head = (f % 192) >> 5;
        int d = f & 31;
        size_t wh2 = (size_t)(win * 6 + head) * 2048;
        if (which == 2) {
            // lane holds 4 CONSECUTIVE n for fixed d -> one 8B store per mt
#pragma unroll
            for (int mt = 0; mt < 4; ++mt) {
                bf16x4 pk;
#pragma unroll
                for (int r = 0; r < 4; ++r) pk[r] = (__bf16)(acc[mt][r] + bb);
                *reinterpret_cast<bf16x4*>(vt + wh2 + d * 64 + mt * 16 + quad * 4) = pk;
            }
        } else {
            float sc = (which == 0) ? 0.17677669529663687f : 1.f;
            bf16* dst = (which == 1) ? k : q;
#pragma unroll
            for (int mt = 0; mt < 4; ++mt)
#pragma unroll
                for (int r = 0; r < 4; ++r) {
                    int n = mt * 16 + quad * 4 + r;
                    dst[wh2 + n * 32 + d] = __float2bfloat16((acc[mt][r] + bb) * sc);
                }
        }
    }
}

// ---------------- Attention (MFMA): one wave per (win, head) ----------------
__global__ __launch_bounds__(256) void attn_kernel(
    const bf16* __restrict__ q, const bf16* __restrict__ k,
    const bf16* __restrict__ vt, const bf16* __restrict__ bmT,
    bf16* __restrict__ ao)
{
    __shared__ __align__(16) bf16 lds[4][64 * 72];
    int wave = threadIdx.x >> 6, lane = threadIdx.x & 63;
    int quad = lane >> 4, l16 = lane & 15;
    int wh = blockIdx.x * 4 + wave;
    int win = wh / 6, head = wh - win * 6;
    const bf16* Qp = q + (size_t)wh * 2048;
    const bf16* Kp = k + (size_t)wh * 2048;
    const bf16* Vp = vt + (size_t)wh * 2048;
    const bf16* bm = bmT + (size_t)((win & 255) * 6 + head) * 4096;

    bf16x8 kf[4], qf[4];
#pragma unroll
    for (int t = 0; t < 4; ++t) {
        kf[t] = ldg8(Kp + (t * 16 + l16) * 32 + quad * 8);
        qf[t] = ldg8(Qp + (t * 16 + l16) * 32 + quad * 8);
    }
    f32x4 s[4][4];
#pragma unroll
    for (int mt = 0; mt < 4; ++mt)
#pragma unroll
        for (int nt = 0; nt < 4; ++nt) {
            f32x4 z = {0.f, 0.f, 0.f, 0.f};
            s[mt][nt] = __builtin_amdgcn_mfma_f32_16x16x32_bf16(kf[mt], qf[nt], z, 0, 0, 0);
        }
    // bias+mask: bmT is [nq][nk]; lane needs nk = mt*16+quad*4..+4 at fixed
    // nq = nt*16+l16 -> one bf16x4 per (mt,nt): 16x 8B instead of 64x 2B.
#pragma unroll
    for (int mt = 0; mt < 4; ++mt)
#pragma unroll
        for (int nt = 0; nt < 4; ++nt) {
            bf16x4 bv = *reinterpret_cast<const bf16x4*>(
                bm + (nt * 16 + l16) * 64 + mt * 16 + quad * 4);
#pragma unroll
            for (int r = 0; r < 4; ++r)
                s[mt][nt][r] += (float)bv[r];
        }
    float linv[4];
#pragma unroll
    for (int nt = 0; nt < 4; ++nt) {
        float mx = -3.0e38f;
#pragma unroll
        for (int mt = 0; mt < 4; ++mt)
#pragma unroll
            for (int r = 0; r < 4; ++r) mx = fmaxf(mx, s[mt][nt][r]);
        mx = fmaxf(mx, __shfl_xor(mx, 16, 64));
        mx = fmaxf(mx, __shfl_xor(mx, 32, 64));
        float sum = 0.f;
#pragma unroll
        for (int mt = 0; mt < 4; ++mt)
#pragma unroll
            for (int r = 0; r < 4; ++r) {
                float p = __expf(s[mt][nt][r] - mx);
                s[mt][nt][r] = p;
                sum += p;
            }
        sum += __shfl_xor(sum, 16, 64);
        sum += __shfl_xor(sum, 32, 64);
        linv[nt] = 1.f / sum;
    }
    // write P[n_q][n_k] * (1/l) to LDS (stride 72)
    bf16* lp = lds[wave];
#pragma unroll
    for (int mt = 0; mt < 4; ++mt)
#pragma unroll
        for (int nt = 0; nt < 4; ++nt)
#pragma unroll
            for (int r = 0; r < 4; ++r)
                lp[(nt * 16 + l16) * 72 + mt * 16 + quad * 4 + r] =
                    __float2bfloat16(s[mt][nt][r] * linv[nt]);
    f32x4 o[4][2];
#pragma unroll
    for (int mo = 0; mo < 4; ++mo)
#pragma unroll
        for (int no = 0; no < 2; ++no) o[mo][no] = (f32x4){0.f, 0.f, 0.f, 0.f};
#pragma unroll
    for (int kh = 0; kh < 2; ++kh) {
        bf16x8 pf[4];
#pragma unroll
        for (int mo = 0; mo < 4; ++mo)
            pf[mo] = *reinterpret_cast<const bf16x8*>(
                lp + (mo * 16 + l16) * 72 + kh * 32 + quad * 8);
#pragma unroll
        for (int no = 0; no < 2; ++no) {
            bf16x8 vf = ldg8(Vp + (no * 16 + l16) * 64 + kh * 32 + quad * 8);
#pragma unroll
            for (int mo = 0; mo < 4; ++mo)
                o[mo][no] = __builtin_amdgcn_mfma_f32_16x16x32_bf16(pf[mo], vf, o[mo][no], 0, 0, 0);
        }
    }
    // store to ao[wh][n][32]
    bf16* ob = ao + (size_t)wh * 2048;
#pragma unroll
    for (int mo = 0; mo < 4; ++mo)
#pragma unroll
        for (int r = 0; r < 4; ++r) {
            int nq = mo * 16 + quad * 4 + r;
            ob[nq * 32 + l16]      = __float2bfloat16(o[mo][0][r]);
            ob[nq * 32 + 16 + l16] = __float2bfloat16(o[mo][1][r]);
        }
}

// ------ Fused proj + LN2 + MLP: one window per block, x1 lives in registers ----
// r12: r10 structure + x residual staged through LDS union (zt == hsh):
// stage loop (12 float4/thread, issued first) -> phase A proj GEMM ->
// barrier -> phase B residual from LDS -> C stats -> D xsn -> E fc1 (hsh
// overwrites zt, safe: >=2 barriers after last zt read) -> F fc2 + x1(regs).
__global__ __launch_bounds__(256, 2) void proj_mlp(
    const bf16* __restrict__ ao, const bf16* __restrict__ Wp,
    const float* __restrict__ pb, const float* __restrict__ x,
    const bf16* __restrict__ W1, const float* __restrict__ b1,
    const bf16* __restrict__ W2, const float* __restrict__ b2,
    float* __restrict__ out)
{
    __shared__ __align__(16) bf16 hsh[64 * 392];     // 50176 B; f32 zt[64][196] alias
    __shared__ __align__(16) bf16 xsn[64 * 200];     // 25600 B
    __shared__ float part[4][64], part2[4][64], ms[64][2];
    float* zt = reinterpret_cast<float*>(hsh);       // [64][196]
    int wave = threadIdx.x >> 6, lane = threadIdx.x & 63;
    int quad = lane >> 4, l16 = lane & 15;
    int win = blockIdx.x;
    int b = win >> 8, wrem = win & 255, wr = wrem >> 4, wc = wrem & 15;

    // ---- stage x window tile into zt (vectorized, row-major coalesced) ----
#pragma unroll 1
    for (int s = 0; s < 12; ++s) {
        int idx = s * 256 + threadIdx.x;             // 64 rows x 48 float4
        int row = idx / 48, c4 = idx - row * 48;
        int ii = row >> 3, jj = row & 7;
        int h = (wr * 8 + ii + 4) & 127, w2 = (wc * 8 + jj + 4) & 127;
        float4 v = *reinterpret_cast<const float4*>(
            x + ((size_t)b * 16384 + h * 128 + w2) * 192 + c4 * 4);
        *reinterpret_cast<float4*>(&zt[row * 196 + c4 * 4]) = v;
    }

    // ---- phase A: proj GEMM; z[i][mt] = x1 tile slice (stays in regs) ----
    f32x4 z[3][4];
    {
        bf16x8 bw[3][6];
#pragma unroll
        for (int i = 0; i < 3; ++i) {
            const bf16* wp = Wp + (size_t)((wave * 3 + i) * 16 + l16) * 192 + quad * 8;
#pragma unroll
            for (int kk = 0; kk < 6; ++kk) bw[i][kk] = ldg8(wp + kk * 32);
        }
#pragma unroll
        for (int mt = 0; mt < 4; ++mt) {
            bf16x8 a6[6];
#pragma unroll
            for (int h = 0; h < 6; ++h)
                a6[h] = ldg8(ao + (size_t)(win * 6 + h) * 2048 + (mt * 16 + l16) * 32 + quad * 8);
#pragma unroll
            for (int i = 0; i < 3; ++i) {
                f32x4 zz = {0.f, 0.f, 0.f, 0.f};
#pragma unroll
                for (int kk = 0; kk < 6; ++kk)
                    zz = __builtin_amdgcn_mfma_f32_16x16x32_bf16(a6[kk], bw[i][kk], zz, 0, 0, 0);
                z[i][mt] = zz;
            }
        }
    }
    __syncthreads();   // zt fully staged (cross-thread) before scattered reads
    // ---- phase B: x1 = proj + pb + x_window (from LDS) ----
#pragma unroll
    for (int i = 0; i < 3; ++i) {
        int c = (wave * 3 + i) * 16 + l16;
        float bb = pb[c];
#pragma unroll
        for (int mt = 0; mt < 4; ++mt)
#pragma unroll
            for (int r = 0; r < 4; ++r) {
                int n = mt * 16 + quad * 4 + r;
                z[i][mt][r] += bb + zt[n * 196 + c];
            }
    }
    // ---- phase C: LN2 stats (cross-wave via LDS partials) ----
#pragma unroll
    for (int mt = 0; mt < 4; ++mt)
#pragma unroll
        for (int r = 0; r < 4; ++r) {
            float s1 = 0.f, s2 = 0.f;
#pragma unroll
            for (int i = 0; i < 3; ++i) {
                float v = z[i][mt][r];
                s1 += v; s2 += v * v;
            }
#pragma unroll
            for (int off = 1; off < 16; off <<= 1) {
                s1 += __shfl_xor(s1, off, 64);
                s2 += __shfl_xor(s2, off, 64);
            }
            if (l16 == 0) {
                int row = mt * 16 + quad * 4 + r;
                part[wave][row] = s1;
                part2[wave][row] = s2;
            }
        }
    __syncthreads();
    if (threadIdx.x < 64) {
        int t = threadIdx.x;
        float S = part[0][t] + part[1][t] + part[2][t] + part[3][t];
        float S2 = part2[0][t] + part2[1][t] + part2[2][t] + part2[3][t];
        float m = S * (1.f / 192.f);
        ms[t][0] = m;
        ms[t][1] = rsqrtf(S2 * (1.f / 192.f) - m * m + 1e-5f);
    }
    __syncthreads();
    // ---- phase D: write normalized bf16 tile to xsn ----
#pragma unroll
    for (int i = 0; i < 3; ++i) {
        int c = (wave * 3 + i) * 16 + l16;
#pragma unroll
        for (int mt = 0; mt < 4; ++mt)
#pragma unroll
            for (int r = 0; r < 4; ++r) {
                int row = mt * 16 + quad * 4 + r;
                xsn[row * 200 + c] =
                    __float2bfloat16((z[i][mt][r] - ms[row][0]) * ms[row][1]);
            }
    }
    __syncthreads();
    // ---- phase E: fc1 + GELU -> hsh (overwrites zt; last zt read was B) ----
    {
        bf16x8 a[4][6];
#pragma unroll
        for (int mt = 0; mt < 4; ++mt)
#pragma unroll
            for (int kk = 0; kk < 6; ++kk)
                a[mt][kk] = *reinterpret_cast<const bf16x8*>(
                    &xsn[(mt * 16 + l16) * 200 + kk * 32 + quad * 8]);
#pragma unroll 1
        for (int i = 0; i < 6; ++i) {
            int nt = wave * 6 + i;
            const bf16* wp = W1 + (size_t)(nt * 16 + l16) * 192 + quad * 8;
            bf16x8 bfr[6];
#pragma unroll
            for (int kk = 0; kk < 6; ++kk) bfr[kk] = ldg8(wp + kk * 32);
            float bb = b1[nt * 16 + l16];
#pragma unroll
            for (int mt = 0; mt < 4; ++mt) {
                f32x4 zz = {0.f, 0.f, 0.f, 0.f};
#pragma unroll
                for (int kk = 0; kk < 6; ++kk)
                    zz = __builtin_amdgcn_mfma_f32_16x16x32_bf16(a[mt][kk], bfr[kk], zz, 0, 0, 0);
#pragma unroll
                for (int r = 0; r < 4; ++r) {
                    float gl = gelu_f(zz[r] + bb);
                    hsh[(mt * 16 + quad * 4 + r) * 392 + nt * 16 + l16] = __float2bfloat16(gl);
                }
            }
        }
    }
    __syncthreads();
    // ---- phase F: fc2 + b2 + x1(regs) -> scatter to out ----
    // FULLY unrolled: z[j][mt] must be compile-time-indexed (rule #20).
#pragma unroll
    for (int j = 0; j < 3; ++j) {
        int c = (wave * 3 + j) * 16 + l16;
        const bf16* wp = W2 + (size_t)c * 384 + quad * 8;
        bf16x8 bw[12];
#pragma unroll
        for (int kk = 0; kk < 12; ++kk) bw[kk] = ldg8(wp + kk * 32);
        float bb = b2[c];
#pragma unroll
        for (int mt = 0; mt < 4; ++mt) {
            f32x4 zz = {0.f, 0.f, 0.f, 0.f};
#pragma unroll
            for (int kk = 0; kk < 12; ++kk) {
                bf16x8 pa = *reinterpret_cast<const bf16x8*>(
                    &hsh[(mt * 16 + l16) * 392 + kk * 32 + quad * 8]);
                zz = __builtin_amdgcn_mfma_f32_16x16x32_bf16(pa, bw[kk], zz, 0, 0, 0);
            }
#pragma unroll
            for (int r = 0; r < 4; ++r) {
                int row = mt * 16 + quad * 4 + r;
                int ii = row >> 3, jj = row & 7;
                int h = (wr * 8 + ii + 4) & 127, w2c = (wc * 8 + jj + 4) & 127;
                size_t didx = ((size_t)b * 16384 + h * 128 + w2c) * 192 + c;
                out[didx] = zz[r] + bb + z[j][mt][r];
            }
        }
    }
}

extern "C" void kernel_launch(void* const* d_in, const int* in_sizes, int n_in,
                              void* d_out, int out_size, void* d_ws, size_t ws_size,
                              hipStream_t stream)
{
    const float* x     = (const float*)d_in[0];
    const float* n1g   = (const float*)d_in[1];
    const float* n1b   = (const float*)d_in[2];
    const float* qkvw  = (const float*)d_in[3];
    const float* qkvb  = (const float*)d_in[4];
    const float* rpb   = (const float*)d_in[5];
    const float* projw = (const float*)d_in[6];
    const float* projb = (const float*)d_in[7];
    const float* n2g   = (const float*)d_in[8];
    const float* n2b   = (const float*)d_in[9];
    const float* fc1w  = (const float*)d_in[10];
    const float* fc1b  = (const float*)d_in[11];
    const float* fc2w  = (const float*)d_in[12];
    const float* fc2b  = (const float*)d_in[13];
    const int*   rel   = (const int*)d_in[14];
    const float* amask = (const float*)d_in[15];
    float* out = (float*)d_out;

    char* ws = (char*)d_ws;
    const size_t SZ = (size_t)131072 * 192 * 2;   // 50,331,648 B per bf16 [T,192]
    bf16* qb  = (bf16*)(ws);                       // q
    bf16* kb  = (bf16*)(ws + SZ);                  // k
    bf16* vtb = (bf16*)(ws + 2 * SZ);              // vt
    bf16* aob = (bf16*)(ws + 3 * SZ);              // attention out
    char* wreg = ws + 4 * SZ;
    bf16*  wq  = (bf16*)(wreg);                    // 110592 el
    bf16*  wp  = wq + 110592;                      // 36864
    bf16*  w1  = wp + 36864;                       // 73728
    bf16*  w2  = w1 + 73728;                       // 73728
    float* bq  = (float*)(w2 + 73728);             // 576 f32
    float* b1  = bq + 576;                         // 384 f32
    bf16*  bmT = (bf16*)(b1 + 384);                // 6,291,456 el (12.6 MB)

    // setup (tiny)
    cvt_scale_kernel<<<108, 256, 0, stream>>>(qkvw, n1g, wq, 110592, 192);
    cvt_scale_kernel<<<36, 256, 0, stream>>>(projw, nullptr, wp, 36864, 192);
    cvt_scale_kernel<<<72, 256, 0, stream>>>(fc1w, n2g, w1, 73728, 192);
    cvt_scale_kernel<<<72, 256, 0, stream>>>(fc2w, nullptr, w2, 73728, 384);
    bias_fold_kernel<<<576, 64, 0, stream>>>(qkvb, qkvw, n1b, bq, 192);
    bias_fold_kernel<<<384, 64, 0, stream>>>(fc1b, fc1w, n2b, b1, 192);
    bm_kernel<<<1536, 256, 0, stream>>>(rpb, rel, amask, bmT);
    // main pipeline
    qkv_ln<<<2048, 256, 0, stream>>>(x, wq, bq, qb, kb, vtb);
    attn_kernel<<<3072, 256, 0, stream>>>(qb, kb, vtb, bmT, aob);
    proj_mlp<<<2048, 256, 0, stream>>>(aob, wp, projb, x, w1, b1, w2, fc2b, out);
}

// Round 9
// 484.470 us; speedup vs baseline: 1.1079x; 1.0475x over previous
//
#include <hip/hip_runtime.h>
#include <hip/hip_bf16.h>

// Swin block, B=8 H=W=128 C=192 HEADS=6 WS=8 SS=4 MLP_H=384
// T = 131072 tokens, 2048 windows (256/batch), N=64, hd=32. I/O f32.
//
// r13: r12 with the staging loop fixed via T14 async-STAGE split.
//   r12's `#pragma unroll 1` staging loop serialized 12 HBM latencies
//   (load -> vmcnt(0) -> ds_write per iteration) = the 184->207 regression.
//   Fix: issue all 12 float4 x-loads into registers st[12] BEFORE phase A
//   (latency hides under the proj GEMM), write them to LDS AFTER phase A,
//   one barrier, phase B reads LDS. st[] fully compile-time-indexed.
//   Keep r12's bmT [nq][nk] layout (attn bias as bf16x4 loads - confirmed win).

typedef __hip_bfloat16 bf16;
typedef __bf16 bf16x8 __attribute__((ext_vector_type(8)));
typedef __bf16 bf16x4 __attribute__((ext_vector_type(4)));
typedef float f32x4 __attribute__((ext_vector_type(4)));

static __device__ __forceinline__ bf16x8 ldg8(const bf16* p) {
    return *reinterpret_cast<const bf16x8*>(p);
}

// GELU with A&S 7.1.26 erf approximation: |err(erf)| <= ~1.5e-6 (f32),
// far below bf16 storage rounding of h. Branch-free, ~16 VALU ops.
static __device__ __forceinline__ float gelu_f(float x) {
    float z  = x * 0.70710678118654752f;
    float az = __builtin_fabsf(z);
    float t  = __builtin_amdgcn_rcpf(__builtin_fmaf(0.3275911f, az, 1.f));
    float p  = __builtin_fmaf(1.061405429f, t, -1.453152027f);
    p = __builtin_fmaf(p, t, 1.421413741f);
    p = __builtin_fmaf(p, t, -0.284496736f);
    p = __builtin_fmaf(p, t, 0.254829592f);
    p = p * t;
    float e  = __expf(-az * az);
    float er = __builtin_fmaf(-p, e, 1.f);        // erf(|z|)
    er = __builtin_copysignf(er, z);
    return 0.5f * x * (1.f + er);
}

// -------- setup: dst[f*K+c] = bf16(src[f*K+c] * g[c]), g==nullptr -> plain ----
__global__ __launch_bounds__(256) void cvt_scale_kernel(
    const float* __restrict__ src, const float* __restrict__ g,
    bf16* __restrict__ dst, int n, int K)
{
    int i = (blockIdx.x * 256 + threadIdx.x) * 4;
    if (i < n) {
        float4 v = *reinterpret_cast<const float4*>(src + i);
        int c = i % K;
        if (g) { v.x *= g[c]; v.y *= g[c + 1]; v.z *= g[c + 2]; v.w *= g[c + 3]; }
        dst[i]     = __float2bfloat16(v.x);
        dst[i + 1] = __float2bfloat16(v.y);
        dst[i + 2] = __float2bfloat16(v.z);
        dst[i + 3] = __float2bfloat16(v.w);
    }
}

// -------- setup: bout[f] = b0[f] + sum_c beta[c] * W[f*K+c]  (one wave per f) ---
__global__ __launch_bounds__(64) void bias_fold_kernel(
    const float* __restrict__ b0, const float* __restrict__ W,
    const float* __restrict__ beta, float* __restrict__ bout, int K)
{
    int f = blockIdx.x, lane = threadIdx.x;
    float s = 0.f;
    for (int c = lane; c < K; c += 64) s += beta[c] * W[(size_t)f * K + c];
#pragma unroll
    for (int off = 32; off; off >>= 1) s += __shfl_xor(s, off, 64);
    if (lane == 0) bout[f] = b0[f] + s;
}

// -------- setup: bias+mask table, layout [wm][head][n_q][n_k] ----------------
__global__ __launch_bounds__(256) void bm_kernel(
    const float* __restrict__ rpb, const int* __restrict__ rel,
    const float* __restrict__ amask, bf16* __restrict__ bmT)
{
    int wm = blockIdx.x / 6, head = blockIdx.x % 6;
    const float* mrow = amask + (size_t)wm * 4096;
    bf16* o = bmT + (size_t)blockIdx.x * 4096;
    for (int idx = threadIdx.x; idx < 4096; idx += 256) {
        // rel/amask are [nq][nk]; keep that order so the consumer can
        // vector-load 4 consecutive nk.
        o[idx] = __float2bfloat16(rpb[rel[idx] * 6 + head] + mrow[idx]);
    }
}

// ---------------- QKV + fused LN1 ----------------
// block 256 = 4 waves; win = blockIdx. Wave w LayerNorms rows 16w..16w+15
// (once), stages normalized bf16 rows in LDS [64][208], all waves re-read
// A-fragments via ds_read_b128, then GEMM + scatter.
__global__ __launch_bounds__(256) void qkv_ln(
    const float* __restrict__ x, const bf16* __restrict__ W,
    const float* __restrict__ bias, bf16* __restrict__ q,
    bf16* __restrict__ k, bf16* __restrict__ vt)
{
    __shared__ __align__(16) bf16 xs[64][208];
    int wave = threadIdx.x >> 6, lane = threadIdx.x & 63;
    int quad = lane >> 4, l16 = lane & 15;
    int win = blockIdx.x;
    int b = win >> 8, wrem = win & 255, wr = wrem >> 4, wc = wrem & 15;

    // --- LN phase: this thread owns cols quad*8+kk*32 of row wave*16+l16 ---
    {
        int n = wave * 16 + l16;
        int ii = n >> 3, jj = n & 7;
        int h = (wr * 8 + ii + 4) & 127, w2 = (wc * 8 + jj + 4) & 127;
        const float* xp = x + ((size_t)b * 16384 + h * 128 + w2) * 192 + quad * 8;
        float e[48];
        float sum = 0.f, sq = 0.f;
#pragma unroll
        for (int kk = 0; kk < 6; ++kk) {
            float4 u0 = *reinterpret_cast<const float4*>(xp + kk * 32);
            float4 u1 = *reinterpret_cast<const float4*>(xp + kk * 32 + 4);
            e[kk * 8 + 0] = u0.x; e[kk * 8 + 1] = u0.y; e[kk * 8 + 2] = u0.z; e[kk * 8 + 3] = u0.w;
            e[kk * 8 + 4] = u1.x; e[kk * 8 + 5] = u1.y; e[kk * 8 + 6] = u1.z; e[kk * 8 + 7] = u1.w;
#pragma unroll
            for (int j = 0; j < 8; ++j) { float v = e[kk * 8 + j]; sum += v; sq += v * v; }
        }
        sum += __shfl_xor(sum, 16, 64); sum += __shfl_xor(sum, 32, 64);
        sq  += __shfl_xor(sq, 16, 64);  sq  += __shfl_xor(sq, 32, 64);
        float mean = sum * (1.f / 192.f);
        float rstd = rsqrtf(sq * (1.f / 192.f) - mean * mean + 1e-5f);
#pragma unroll
        for (int kk = 0; kk < 6; ++kk) {
            bf16x8 pk;
#pragma unroll
            for (int j = 0; j < 8; ++j)
                pk[j] = (__bf16)((e[kk * 8 + j] - mean) * rstd);
            *reinterpret_cast<bf16x8*>(&xs[n][kk * 32 + quad * 8]) = pk;
        }
    }
    __syncthreads();
    // --- load A fragments from LDS (shared across waves) ---
    bf16x8 a[4][6];
#pragma unroll
    for (int mt = 0; mt < 4; ++mt)
#pragma unroll
        for (int kk = 0; kk < 6; ++kk)
            a[mt][kk] = *reinterpret_cast<const bf16x8*>(&xs[mt * 16 + l16][kk * 32 + quad * 8]);

#pragma unroll 1
    for (int i = 0; i < 9; ++i) {
        int nt = wave * 9 + i;
        const bf16* wrow = W + (size_t)(nt * 16 + l16) * 192 + quad * 8;
        bf16x8 bfr[6];
#pragma unroll
        for (int kk = 0; kk < 6; ++kk) bfr[kk] = ldg8(wrow + kk * 32);
        f32x4 acc[4];
#pragma unroll
        for (int mt = 0; mt < 4; ++mt) {
            f32x4 z = {0.f, 0.f, 0.f, 0.f};
#pragma unroll
            for (int kk = 0; kk < 6; ++kk)
                z = __builtin_amdgcn_mfma_f32_16x16x32_bf16(a[mt][kk], bfr[kk], z, 0, 0, 0);
            acc[mt] = z;
        }
        int f = nt * 16 + l16;
        float bb = bias[f];
        int which = f / 192;           // uniform per (wave,i)
        int head = (f % 192) >> 5;
        int d = f & 31;
        size_t wh2 = (size_t)(win * 6 + head) * 2048;
        if (which == 2) {
            // lane holds 4 CONSECUTIVE n for fixed d -> one 8B store per mt
#pragma unroll
            for (int mt = 0; mt < 4; ++mt) {
                bf16x4 pk;
#pragma unroll
                for (int r = 0; r < 4; ++r) pk[r] = (__bf16)(acc[mt][r] + bb);
                *reinterpret_cast<bf16x4*>(vt + wh2 + d * 64 + mt * 16 + quad * 4) = pk;
            }
        } else {
            float sc = (which == 0) ? 0.17677669529663687f : 1.f;
            bf16* dst = (which == 1) ? k : q;
#pragma unroll
            for (int mt = 0; mt < 4; ++mt)
#pragma unroll
                for (int r = 0; r < 4; ++r) {
                    int n = mt * 16 + quad * 4 + r;
                    dst[wh2 + n * 32 + d] = __float2bfloat16((acc[mt][r] + bb) * sc);
                }
        }
    }
}

// ---------------- Attention (MFMA): one wave per (win, head) ----------------
__global__ __launch_bounds__(256) void attn_kernel(
    const bf16* __restrict__ q, const bf16* __restrict__ k,
    const bf16* __restrict__ vt, const bf16* __restrict__ bmT,
    bf16* __restrict__ ao)
{
    __shared__ __align__(16) bf16 lds[4][64 * 72];
    int wave = threadIdx.x >> 6, lane = threadIdx.x & 63;
    int quad = lane >> 4, l16 = lane & 15;
    int wh = blockIdx.x * 4 + wave;
    int win = wh / 6, head = wh - win * 6;
    const bf16* Qp = q + (size_t)wh * 2048;
    const bf16* Kp = k + (size_t)wh * 2048;
    const bf16* Vp = vt + (size_t)wh * 2048;
    const bf16* bm = bmT + (size_t)((win & 255) * 6 + head) * 4096;

    bf16x8 kf[4], qf[4];
#pragma unroll
    for (int t = 0; t < 4; ++t) {
        kf[t] = ldg8(Kp + (t * 16 + l16) * 32 + quad * 8);
        qf[t] = ldg8(Qp + (t * 16 + l16) * 32 + quad * 8);
    }
    f32x4 s[4][4];
#pragma unroll
    for (int mt = 0; mt < 4; ++mt)
#pragma unroll
        for (int nt = 0; nt < 4; ++nt) {
            f32x4 z = {0.f, 0.f, 0.f, 0.f};
            s[mt][nt] = __builtin_amdgcn_mfma_f32_16x16x32_bf16(kf[mt], qf[nt], z, 0, 0, 0);
        }
    // bias+mask: bmT is [nq][nk]; lane needs nk = mt*16+quad*4..+4 at fixed
    // nq = nt*16+l16 -> one bf16x4 per (mt,nt): 16x 8B instead of 64x 2B.
#pragma unroll
    for (int mt = 0; mt < 4; ++mt)
#pragma unroll
        for (int nt = 0; nt < 4; ++nt) {
            bf16x4 bv = *reinterpret_cast<const bf16x4*>(
                bm + (nt * 16 + l16) * 64 + mt * 16 + quad * 4);
#pragma unroll
            for (int r = 0; r < 4; ++r)
                s[mt][nt][r] += (float)bv[r];
        }
    float linv[4];
#pragma unroll
    for (int nt = 0; nt < 4; ++nt) {
        float mx = -3.0e38f;
#pragma unroll
        for (int mt = 0; mt < 4; ++mt)
#pragma unroll
            for (int r = 0; r < 4; ++r) mx = fmaxf(mx, s[mt][nt][r]);
        mx = fmaxf(mx, __shfl_xor(mx, 16, 64));
        mx = fmaxf(mx, __shfl_xor(mx, 32, 64));
        float sum = 0.f;
#pragma unroll
        for (int mt = 0; mt < 4; ++mt)
#pragma unroll
            for (int r = 0; r < 4; ++r) {
                float p = __expf(s[mt][nt][r] - mx);
                s[mt][nt][r] = p;
                sum += p;
            }
        sum += __shfl_xor(sum, 16, 64);
        sum += __shfl_xor(sum, 32, 64);
        linv[nt] = 1.f / sum;
    }
    // write P[n_q][n_k] * (1/l) to LDS (stride 72)
    bf16* lp = lds[wave];
#pragma unroll
    for (int mt = 0; mt < 4; ++mt)
#pragma unroll
        for (int nt = 0; nt < 4; ++nt)
#pragma unroll
            for (int r = 0; r < 4; ++r)
                lp[(nt * 16 + l16) * 72 + mt * 16 + quad * 4 + r] =
                    __float2bfloat16(s[mt][nt][r] * linv[nt]);
    f32x4 o[4][2];
#pragma unroll
    for (int mo = 0; mo < 4; ++mo)
#pragma unroll
        for (int no = 0; no < 2; ++no) o[mo][no] = (f32x4){0.f, 0.f, 0.f, 0.f};
#pragma unroll
    for (int kh = 0; kh < 2; ++kh) {
        bf16x8 pf[4];
#pragma unroll
        for (int mo = 0; mo < 4; ++mo)
            pf[mo] = *reinterpret_cast<const bf16x8*>(
                lp + (mo * 16 + l16) * 72 + kh * 32 + quad * 8);
#pragma unroll
        for (int no = 0; no < 2; ++no) {
            bf16x8 vf = ldg8(Vp + (no * 16 + l16) * 64 + kh * 32 + quad * 8);
#pragma unroll
            for (int mo = 0; mo < 4; ++mo)
                o[mo][no] = __builtin_amdgcn_mfma_f32_16x16x32_bf16(pf[mo], vf, o[mo][no], 0, 0, 0);
        }
    }
    // store to ao[wh][n][32]
    bf16* ob = ao + (size_t)wh * 2048;
#pragma unroll
    for (int mo = 0; mo < 4; ++mo)
#pragma unroll
        for (int r = 0; r < 4; ++r) {
            int nq = mo * 16 + quad * 4 + r;
            ob[nq * 32 + l16]      = __float2bfloat16(o[mo][0][r]);
            ob[nq * 32 + 16 + l16] = __float2bfloat16(o[mo][1][r]);
        }
}

// ------ Fused proj + LN2 + MLP: one window per block, x1 lives in registers ----
// r13: T14 async-STAGE split for the x residual:
//   issue 12 float4 loads -> st[12] regs (EARLY, before phase A) ->
//   phase A proj GEMM (HBM latency hides underneath) ->
//   write st[] -> zt LDS (LATE) -> barrier -> phase B reads LDS.
// zt aliases hsh (dead until phase E). All reg arrays compile-time-indexed.
__global__ __launch_bounds__(256, 2) void proj_mlp(
    const bf16* __restrict__ ao, const bf16* __restrict__ Wp,
    const float* __restrict__ pb, const float* __restrict__ x,
    const bf16* __restrict__ W1, const float* __restrict__ b1,
    const bf16* __restrict__ W2, const float* __restrict__ b2,
    float* __restrict__ out)
{
    __shared__ __align__(16) bf16 hsh[64 * 392];     // 50176 B; f32 zt[64][196] alias
    __shared__ __align__(16) bf16 xsn[64 * 200];     // 25600 B
    __shared__ float part[4][64], part2[4][64], ms[64][2];
    float* zt = reinterpret_cast<float*>(hsh);       // [64][196]
    int wave = threadIdx.x >> 6, lane = threadIdx.x & 63;
    int quad = lane >> 4, l16 = lane & 15;
    int win = blockIdx.x;
    int b = win >> 8, wrem = win & 255, wr = wrem >> 4, wc = wrem & 15;

    // ---- T14 issue-early: x window tile -> st[12] registers ----
    float4 st[12];
#pragma unroll
    for (int s = 0; s < 12; ++s) {
        int idx = s * 256 + threadIdx.x;             // 64 rows x 48 float4
        int row = idx / 48, c4 = idx - row * 48;
        int ii = row >> 3, jj = row & 7;
        int h = (wr * 8 + ii + 4) & 127, w2 = (wc * 8 + jj + 4) & 127;
        st[s] = *reinterpret_cast<const float4*>(
            x + ((size_t)b * 16384 + h * 128 + w2) * 192 + c4 * 4);
    }

    // ---- phase A: proj GEMM; z[i][mt] = x1 tile slice (stays in regs) ----
    f32x4 z[3][4];
    {
        bf16x8 bw[3][6];
#pragma unroll
        for (int i = 0; i < 3; ++i) {
            const bf16* wp = Wp + (size_t)((wave * 3 + i) * 16 + l16) * 192 + quad * 8;
#pragma unroll
            for (int kk = 0; kk < 6; ++kk) bw[i][kk] = ldg8(wp + kk * 32);
        }
#pragma unroll
        for (int mt = 0; mt < 4; ++mt) {
            bf16x8 a6[6];
#pragma unroll
            for (int h = 0; h < 6; ++h)
                a6[h] = ldg8(ao + (size_t)(win * 6 + h) * 2048 + (mt * 16 + l16) * 32 + quad * 8);
#pragma unroll
            for (int i = 0; i < 3; ++i) {
                f32x4 zz = {0.f, 0.f, 0.f, 0.f};
#pragma unroll
                for (int kk = 0; kk < 6; ++kk)
                    zz = __builtin_amdgcn_mfma_f32_16x16x32_bf16(a6[kk], bw[i][kk], zz, 0, 0, 0);
                z[i][mt] = zz;
            }
        }
    }
    // ---- T14 write-late: staged x -> zt LDS ----
#pragma unroll
    for (int s = 0; s < 12; ++s) {
        int idx = s * 256 + threadIdx.x;
        int row = idx / 48, c4 = idx - row * 48;
        *reinterpret_cast<float4*>(&zt[row * 196 + c4 * 4]) = st[s];
    }
    __syncthreads();   // zt fully staged before scattered reads
    // ---- phase B: x1 = proj + pb + x_window (from LDS) ----
#pragma unroll
    for (int i = 0; i < 3; ++i) {
        int c = (wave * 3 + i) * 16 + l16;
        float bb = pb[c];
#pragma unroll
        for (int mt = 0; mt < 4; ++mt)
#pragma unroll
            for (int r = 0; r < 4; ++r) {
                int n = mt * 16 + quad * 4 + r;
                z[i][mt][r] += bb + zt[n * 196 + c];
            }
    }
    // ---- phase C: LN2 stats (cross-wave via LDS partials) ----
#pragma unroll
    for (int mt = 0; mt < 4; ++mt)
#pragma unroll
        for (int r = 0; r < 4; ++r) {
            float s1 = 0.f, s2 = 0.f;
#pragma unroll
            for (int i = 0; i < 3; ++i) {
                float v = z[i][mt][r];
                s1 += v; s2 += v * v;
            }
#pragma unroll
            for (int off = 1; off < 16; off <<= 1) {
                s1 += __shfl_xor(s1, off, 64);
                s2 += __shfl_xor(s2, off, 64);
            }
            if (l16 == 0) {
                int row = mt * 16 + quad * 4 + r;
                part[wave][row] = s1;
                part2[wave][row] = s2;
            }
        }
    __syncthreads();
    if (threadIdx.x < 64) {
        int t = threadIdx.x;
        float S = part[0][t] + part[1][t] + part[2][t] + part[3][t];
        float S2 = part2[0][t] + part2[1][t] + part2[2][t] + part2[3][t];
        float m = S * (1.f / 192.f);
        ms[t][0] = m;
        ms[t][1] = rsqrtf(S2 * (1.f / 192.f) - m * m + 1e-5f);
    }
    __syncthreads();
    // ---- phase D: write normalized bf16 tile to xsn ----
#pragma unroll
    for (int i = 0; i < 3; ++i) {
        int c = (wave * 3 + i) * 16 + l16;
#pragma unroll
        for (int mt = 0; mt < 4; ++mt)
#pragma unroll
            for (int r = 0; r < 4; ++r) {
                int row = mt * 16 + quad * 4 + r;
                xsn[row * 200 + c] =
                    __float2bfloat16((z[i][mt][r] - ms[row][0]) * ms[row][1]);
            }
    }
    __syncthreads();
    // ---- phase E: fc1 + GELU -> hsh (overwrites zt; last zt read was B) ----
    {
        bf16x8 a[4][6];
#pragma unroll
        for (int mt = 0; mt < 4; ++mt)
#pragma unroll
            for (int kk = 0; kk < 6; ++kk)
                a[mt][kk] = *reinterpret_cast<const bf16x8*>(
                    &xsn[(mt * 16 + l16) * 200 + kk * 32 + quad * 8]);
#pragma unroll 1
        for (int i = 0; i < 6; ++i) {
            int nt = wave * 6 + i;
            const bf16* wp = W1 + (size_t)(nt * 16 + l16) * 192 + quad * 8;
            bf16x8 bfr[6];
#pragma unroll
            for (int kk = 0; kk < 6; ++kk) bfr[kk] = ldg8(wp + kk * 32);
            float bb = b1[nt * 16 + l16];
#pragma unroll
            for (int mt = 0; mt < 4; ++mt) {
                f32x4 zz = {0.f, 0.f, 0.f, 0.f};
#pragma unroll
                for (int kk = 0; kk < 6; ++kk)
                    zz = __builtin_amdgcn_mfma_f32_16x16x32_bf16(a[mt][kk], bfr[kk], zz, 0, 0, 0);
#pragma unroll
                for (int r = 0; r < 4; ++r) {
                    float gl = gelu_f(zz[r] + bb);
                    hsh[(mt * 16 + quad * 4 + r) * 392 + nt * 16 + l16] = __float2bfloat16(gl);
                }
            }
        }
    }
    __syncthreads();
    // ---- phase F: fc2 + b2 + x1(regs) -> scatter to out ----
    // FULLY unrolled: z[j][mt] must be compile-time-indexed (rule #20).
#pragma unroll
    for (int j = 0; j < 3; ++j) {
        int c = (wave * 3 + j) * 16 + l16;
        const bf16* wp = W2 + (size_t)c * 384 + quad * 8;
        bf16x8 bw[12];
#pragma unroll
        for (int kk = 0; kk < 12; ++kk) bw[kk] = ldg8(wp + kk * 32);
        float bb = b2[c];
#pragma unroll
        for (int mt = 0; mt < 4; ++mt) {
            f32x4 zz = {0.f, 0.f, 0.f, 0.f};
#pragma unroll
            for (int kk = 0; kk < 12; ++kk) {
                bf16x8 pa = *reinterpret_cast<const bf16x8*>(
                    &hsh[(mt * 16 + l16) * 392 + kk * 32 + quad * 8]);
                zz = __builtin_amdgcn_mfma_f32_16x16x32_bf16(pa, bw[kk], zz, 0, 0, 0);
            }
#pragma unroll
            for (int r = 0; r < 4; ++r) {
                int row = mt * 16 + quad * 4 + r;
                int ii = row >> 3, jj = row & 7;
                int h = (wr * 8 + ii + 4) & 127, w2c = (wc * 8 + jj + 4) & 127;
                size_t didx = ((size_t)b * 16384 + h * 128 + w2c) * 192 + c;
                out[didx] = zz[r] + bb + z[j][mt][r];
            }
        }
    }
}

extern "C" void kernel_launch(void* const* d_in, const int* in_sizes, int n_in,
                              void* d_out, int out_size, void* d_ws, size_t ws_size,
                              hipStream_t stream)
{
    const float* x     = (const float*)d_in[0];
    const float* n1g   = (const float*)d_in[1];
    const float* n1b   = (const float*)d_in[2];
    const float* qkvw  = (const float*)d_in[3];
    const float* qkvb  = (const float*)d_in[4];
    const float* rpb   = (const float*)d_in[5];
    const float* projw = (const float*)d_in[6];
    const float* projb = (const float*)d_in[7];
    const float* n2g   = (const float*)d_in[8];
    const float* n2b   = (const float*)d_in[9];
    const float* fc1w  = (const float*)d_in[10];
    const float* fc1b  = (const float*)d_in[11];
    const float* fc2w  = (const float*)d_in[12];
    const float* fc2b  = (const float*)d_in[13];
    const int*   rel   = (const int*)d_in[14];
    const float* amask = (const float*)d_in[15];
    float* out = (float*)d_out;

    char* ws = (char*)d_ws;
    const size_t SZ = (size_t)131072 * 192 * 2;   // 50,331,648 B per bf16 [T,192]
    bf16* qb  = (bf16*)(ws);                       // q
    bf16* kb  = (bf16*)(ws + SZ);                  // k
    bf16* vtb = (bf16*)(ws + 2 * SZ);              // vt
    bf16* aob = (bf16*)(ws + 3 * SZ);              // attention out
    char* wreg = ws + 4 * SZ;
    bf16*  wq  = (bf16*)(wreg);                    // 110592 el
    bf16*  wp  = wq + 110592;                      // 36864
    bf16*  w1  = wp + 36864;                       // 73728
    bf16*  w2  = w1 + 73728;                       // 73728
    float* bq  = (float*)(w2 + 73728);             // 576 f32
    float* b1  = bq + 576;                         // 384 f32
    bf16*  bmT = (bf16*)(b1 + 384);                // 6,291,456 el (12.6 MB)

    // setup (tiny)
    cvt_scale_kernel<<<108, 256, 0, stream>>>(qkvw, n1g, wq, 110592, 192);
    cvt_scale_kernel<<<36, 256, 0, stream>>>(projw, nullptr, wp, 36864, 192);
    cvt_scale_kernel<<<72, 256, 0, stream>>>(fc1w, n2g, w1, 73728, 192);
    cvt_scale_kernel<<<72, 256, 0, stream>>>(fc2w, nullptr, w2, 73728, 384);
    bias_fold_kernel<<<576, 64, 0, stream>>>(qkvb, qkvw, n1b, bq, 192);
    bias_fold_kernel<<<384, 64, 0, stream>>>(fc1b, fc1w, n2b, b1, 192);
    bm_kernel<<<1536, 256, 0, stream>>>(rpb, rel, amask, bmT);
    // main pipeline
    qkv_ln<<<2048, 256, 0, stream>>>(x, wq, bq, qb, kb, vtb);
    attn_kernel<<<3072, 256, 0, stream>>>(qb, kb, vtb, bmT, aob);
    proj_mlp<<<2048, 256, 0, stream>>>(aob, wp, projb, x, w1, b1, w2, fc2b, out);
}